// Round 1
// baseline (1039.127 us; speedup 1.0000x reference)
//
#include <hip/hip_runtime.h>
#include <math.h>

#define BB 2
#define NN 4096
#define CC 128
#define TK 8
#define USTR 4104

// f64-accurate constants, rounded by compiler to f32 (matches jnp.full(...f32))
#define NORM_C  (-9.010913347279288f)   // -log(8192)
#define DUST_C  (-0.6931471805599453f)  // log(4096) - log(8192)

__device__ __forceinline__ void olse(float& mx, float& sm, float val){
  if (val <= mx) sm += expf(val - mx);
  else { sm = sm * expf(mx - val) + 1.0f; mx = val; }
}
__device__ __forceinline__ void lse_merge(float& mx, float& sm, float omx, float osm){
  if (omx <= mx) sm += osm * expf(omx - mx);
  else { sm = sm * expf(mx - omx) + osm; mx = omx; }
}
__device__ __forceinline__ void wave_lse(float& mx, float& sm){
  #pragma unroll
  for (int off = 32; off > 0; off >>= 1){
    float omx = __shfl_xor(mx, off);
    float osm = __shfl_xor(sm, off);
    lse_merge(mx, sm, omx, osm);
  }
}

// ---------------- normalize: both feats, one wave per row ----------------
extern "C" __global__ __launch_bounds__(256)
void k_norm(const float* __restrict__ fA, const float* __restrict__ fB,
            float* __restrict__ nA, float* __restrict__ nB){
  int gw   = (blockIdx.x * 256 + threadIdx.x) >> 6;   // global wave id, 0..16383
  int lane = threadIdx.x & 63;
  const float* src; float* dst;
  if (gw < BB*NN){ src = fA + (size_t)gw*CC; dst = nA + (size_t)gw*CC; }
  else { int r = gw - BB*NN; src = fB + (size_t)r*CC; dst = nB + (size_t)r*CC; }
  float2 x = ((const float2*)src)[lane];
  float ss = x.x*x.x + x.y*x.y;
  #pragma unroll
  for (int off = 32; off > 0; off >>= 1) ss += __shfl_xor(ss, off);
  float inv = 1.0f / fmaxf(sqrtf(ss), 1e-12f);
  ((float2*)dst)[lane] = make_float2(x.x*inv, x.y*inv);
}

// ---------------- f32 GEMM: sim = nA @ nB^T, 128x128 tile, 8x8 microtile ----------------
extern "C" __global__ __launch_bounds__(256)
void k_gemm(const float* __restrict__ nA, const float* __restrict__ nB, float* __restrict__ sim){
  __shared__ float sA[32][132];  // [k][m], 16B-aligned rows (132*4=528)
  __shared__ float sB[32][132];
  const int t  = threadIdx.x;
  const int b  = blockIdx.z;
  const int m0 = blockIdx.y << 7, n0 = blockIdx.x << 7;
  const float* Ab = nA + ((size_t)b*NN + m0)*CC;
  const float* Bb = nB + ((size_t)b*NN + n0)*CC;
  const int tx = t & 15, ty = t >> 4;
  float acc[8][8];
  #pragma unroll
  for (int i = 0; i < 8; i++)
    #pragma unroll
    for (int j = 0; j < 8; j++) acc[i][j] = 0.f;

  #pragma unroll 1
  for (int kc = 0; kc < 4; kc++){
    if (kc) __syncthreads();
    #pragma unroll
    for (int i = 0; i < 4; i++){
      int fi = t + (i << 8);         // 0..1023
      int r  = fi >> 3, c4 = fi & 7; // row 0..127, float4 idx in 32-col chunk
      float4 av = *(const float4*)(Ab + (size_t)r*CC + (kc<<5) + (c4<<2));
      float4 bv = *(const float4*)(Bb + (size_t)r*CC + (kc<<5) + (c4<<2));
      int kk = c4 << 2;
      sA[kk+0][r]=av.x; sA[kk+1][r]=av.y; sA[kk+2][r]=av.z; sA[kk+3][r]=av.w;
      sB[kk+0][r]=bv.x; sB[kk+1][r]=bv.y; sB[kk+2][r]=bv.z; sB[kk+3][r]=bv.w;
    }
    __syncthreads();
    #pragma unroll 4
    for (int k = 0; k < 32; k++){
      float4 a0 = *(const float4*)&sA[k][ty<<2];
      float4 a1 = *(const float4*)&sA[k][64 + (ty<<2)];
      float4 b0 = *(const float4*)&sB[k][tx<<2];
      float4 b1 = *(const float4*)&sB[k][64 + (tx<<2)];
      float av[8] = {a0.x,a0.y,a0.z,a0.w,a1.x,a1.y,a1.z,a1.w};
      float bw[8] = {b0.x,b0.y,b0.z,b0.w,b1.x,b1.y,b1.z,b1.w};
      #pragma unroll
      for (int i = 0; i < 8; i++)
        #pragma unroll
        for (int j = 0; j < 8; j++)
          acc[i][j] = fmaf(av[i], bw[j], acc[i][j]);
    }
  }
  float* Cb = sim + ((size_t)b*NN + m0)*NN + n0;
  #pragma unroll
  for (int i = 0; i < 8; i++){
    int mr = (i < 4) ? ((ty<<2) + i) : (64 + (ty<<2) + (i-4));
    float* cp = Cb + (size_t)mr*NN;
    *(float4*)(cp + (tx<<2))      = make_float4(acc[i][0],acc[i][1],acc[i][2],acc[i][3]);
    *(float4*)(cp + 64 + (tx<<2)) = make_float4(acc[i][4],acc[i][5],acc[i][6],acc[i][7]);
  }
}

// ---------------- Sinkhorn u-update: one block per row (incl. dustbin row) ----------------
extern "C" __global__ __launch_bounds__(256)
void k_u(const float* __restrict__ sim, const float* __restrict__ v, float* __restrict__ u,
         const float* __restrict__ dsp, const float* __restrict__ tpp){
  int row = blockIdx.x, b = blockIdx.y, t = threadIdx.x;
  float invt = 1.0f / tpp[0], ds = dsp[0];
  const float* vb = v + b*USTR;
  float mx = -INFINITY, sm = 0.f;
  if (row < NN){
    const float* sr = sim + ((size_t)b*NN + row)*NN;
    #pragma unroll
    for (int i = 0; i < 16; i++){ int n = t + (i<<8); olse(mx, sm, sr[n]*invt + vb[n]); }
  } else {
    #pragma unroll
    for (int i = 0; i < 16; i++){ int n = t + (i<<8); olse(mx, sm, ds + vb[n]); }
  }
  if (t == 0) olse(mx, sm, (row < NN ? ds : 0.0f) + vb[NN]);
  wave_lse(mx, sm);
  __shared__ float smx[4], ssm[4];
  if ((t & 63) == 0){ smx[t>>6] = mx; ssm[t>>6] = sm; }
  __syncthreads();
  if (t == 0){
    #pragma unroll
    for (int i = 1; i < 4; i++) lse_merge(mx, sm, smx[i], ssm[i]);
    u[b*USTR + row] = (row < NN ? NORM_C : DUST_C) - (mx + logf(sm));
  }
}

// ---------------- Sinkhorn v-update stage A: partial column LSE over 256-row chunks ----------------
extern "C" __global__ __launch_bounds__(256)
void k_vA(const float* __restrict__ sim, const float* __restrict__ u,
          float* __restrict__ pmax, float* __restrict__ psum, const float* __restrict__ tpp){
  int t = threadIdx.x;
  int n = blockIdx.x*256 + t;
  int chunk = blockIdx.y, b = blockIdx.z;
  float invt = 1.0f / tpp[0];
  __shared__ float su[256];
  su[t] = u[b*USTR + (chunk<<8) + t];
  __syncthreads();
  const float* sp = sim + ((size_t)b*NN + (chunk<<8))*NN + n;
  float mx = -INFINITY, sm = 0.f;
  #pragma unroll 8
  for (int r = 0; r < 256; r++){
    olse(mx, sm, sp[(size_t)r*NN]*invt + su[r]);
  }
  int o = (b*16 + chunk)*NN + n;
  pmax[o] = mx; psum[o] = sm;
}

// ---------------- Sinkhorn v-update stage B: merge chunks + dustbin handling ----------------
extern "C" __global__ __launch_bounds__(256)
void k_vB(const float* __restrict__ pmax, const float* __restrict__ psum,
          const float* __restrict__ u, float* __restrict__ v, const float* __restrict__ dsp){
  int t = threadIdx.x, b = blockIdx.z;
  float ds = dsp[0];
  if (blockIdx.x < 16){
    int n = blockIdx.x*256 + t;
    float mx = pmax[(b*16)*NN + n], sm = psum[(b*16)*NN + n];
    #pragma unroll
    for (int c = 1; c < 16; c++) lse_merge(mx, sm, pmax[(b*16+c)*NN + n], psum[(b*16+c)*NN + n]);
    olse(mx, sm, ds + u[b*USTR + NN]);          // dustbin row M
    v[b*USTR + n] = NORM_C - (mx + logf(sm));
  } else {
    // dustbin column N: lse over (ds + u[m]) for m<M, plus u[M]
    float mx = -INFINITY, sm = 0.f;
    #pragma unroll
    for (int i = 0; i < 16; i++){ int m = t + (i<<8); olse(mx, sm, ds + u[b*USTR + m]); }
    if (t == 0) olse(mx, sm, u[b*USTR + NN]);
    wave_lse(mx, sm);
    __shared__ float smx[4], ssm[4];
    if ((t & 63) == 0){ smx[t>>6] = mx; ssm[t>>6] = sm; }
    __syncthreads();
    if (t == 0){
      #pragma unroll
      for (int i = 1; i < 4; i++) lse_merge(mx, sm, smx[i], ssm[i]);
      v[b*USTR + NN] = DUST_C - (mx + logf(sm));
    }
  }
}

// ---------------- final fused row pass: probs, entropy, base_expected, top-8 ----------------
extern "C" __global__ __launch_bounds__(256)
void k_final(const float* __restrict__ sim, const float* __restrict__ u, const float* __restrict__ v,
             const float* __restrict__ posB, float* __restrict__ entO,
             float* __restrict__ tval, int* __restrict__ tidx, float* __restrict__ tpos,
             float* __restrict__ bexp, const float* __restrict__ tpp){
  int m = blockIdx.x, b = blockIdx.y, t = threadIdx.x;
  float invt = 1.0f / tpp[0];
  const float* sr = sim + ((size_t)b*NN + m)*NN;
  const float* vb = v + b*USTR;
  float um = u[b*USTR + m];
  float p[16];
  float s_loc = 0.f;
  #pragma unroll
  for (int i = 0; i < 16; i++){
    int n = t + (i<<8);
    float la = sr[n]*invt + um + vb[n];
    p[i] = expf(la);
    s_loc += p[i];
  }
  #pragma unroll
  for (int off = 32; off > 0; off >>= 1) s_loc += __shfl_xor(s_loc, off);
  __shared__ float rs[4];
  if ((t & 63) == 0) rs[t>>6] = s_loc;
  __syncthreads();
  float Sp = (rs[0]+rs[1]+rs[2]+rs[3]) + 1e-8f;

  const float2* pb = (const float2*)(posB + (size_t)b*NN*2);
  float e = 0.f, bx = 0.f, by = 0.f;
  #pragma unroll
  for (int i = 0; i < 16; i++){
    int n = t + (i<<8);
    float pd = p[i] / Sp;
    e -= pd * logf(pd + 1e-8f);
    float2 q = pb[n];
    bx = fmaf(pd, q.x, bx); by = fmaf(pd, q.y, by);
  }
  #pragma unroll
  for (int off = 32; off > 0; off >>= 1){
    e  += __shfl_xor(e, off);
    bx += __shfl_xor(bx, off);
    by += __shfl_xor(by, off);
  }
  __shared__ float re[4], rbx[4], rby[4];
  if ((t & 63) == 0){ re[t>>6] = e; rbx[t>>6] = bx; rby[t>>6] = by; }
  __syncthreads();
  if (t == 0){
    entO[(size_t)b*NN + m] = re[0]+re[1]+re[2]+re[3];
    bexp[((size_t)b*NN + m)*2 + 0] = rbx[0]+rbx[1]+rbx[2]+rbx[3];
    bexp[((size_t)b*NN + m)*2 + 1] = rby[0]+rby[1]+rby[2]+rby[3];
  }

  // top-8 (jax tie-break: lower index wins)
  __shared__ float wv[4]; __shared__ int wi[4];
  size_t obase = ((size_t)b*NN + m)*TK;
  for (int r = 0; r < TK; r++){
    float bv = -INFINITY; int bi = 0;
    #pragma unroll
    for (int i = 0; i < 16; i++){ int n = t + (i<<8); if (p[i] > bv){ bv = p[i]; bi = n; } }
    #pragma unroll
    for (int off = 32; off > 0; off >>= 1){
      float ov = __shfl_xor(bv, off); int oi = __shfl_xor(bi, off);
      if (ov > bv || (ov == bv && oi < bi)){ bv = ov; bi = oi; }
    }
    if ((t & 63) == 0){ wv[t>>6] = bv; wi[t>>6] = bi; }
    __syncthreads();
    float Wv = wv[0]; int Wi = wi[0];
    #pragma unroll
    for (int i = 1; i < 4; i++){ if (wv[i] > Wv || (wv[i] == Wv && wi[i] < Wi)){ Wv = wv[i]; Wi = wi[i]; } }
    if (t == (Wi & 255)){
      int sl = Wi >> 8;
      #pragma unroll
      for (int i = 0; i < 16; i++) if (i == sl) p[i] = -INFINITY;  // static idx only
    }
    if (t == 0){
      tval[obase + r] = Wv; tidx[obase + r] = Wi;
      tpos[(obase + r)*2 + 0] = posB[((size_t)b*NN + Wi)*2 + 0];
      tpos[(obase + r)*2 + 1] = posB[((size_t)b*NN + Wi)*2 + 1];
    }
    __syncthreads();
  }
}

// ---------------- geometric scores: per (b,k) 64x64 disp image, 7x7 box stats ----------------
extern "C" __global__ __launch_bounds__(1024)
void k_geo(const float* __restrict__ posA, const float* __restrict__ tpos,
           float* __restrict__ geoO){
  int k = blockIdx.x, b = blockIdx.y, t = threadIdx.x;
  __shared__ float dx[4096], dy[4096];
  #pragma unroll
  for (int i = 0; i < 4; i++){
    int px = t + (i<<10);
    float2 c = *(const float2*)(tpos + (((size_t)b*NN + px)*TK + k)*2);
    float2 s = *(const float2*)(posA + ((size_t)b*NN + px)*2);
    dx[px] = c.x - s.x; dy[px] = c.y - s.y;
  }
  __syncthreads();
  #pragma unroll
  for (int i = 0; i < 4; i++){
    int px = t + (i<<10);
    int h = px >> 6, w = px & 63;
    int h0 = max(h-3, 0), h1 = min(h+3, 63);
    int w0 = max(w-3, 0), w1 = min(w+3, 63);
    float sx = 0.f, sxx = 0.f, sy = 0.f, syy = 0.f;
    for (int hh = h0; hh <= h1; hh++){
      int ro = hh << 6;
      for (int ww = w0; ww <= w1; ww++){
        float a = dx[ro + ww]; sx += a; sxx = fmaf(a, a, sxx);
        float c2 = dy[ro + ww]; sy += c2; syy = fmaf(c2, c2, syy);
      }
    }
    float rc = 1.0f / (float)((h1-h0+1)*(w1-w0+1));
    float mxm = sx*rc, mym = sy*rc;
    float vx = fmaxf(sxx*rc - mxm*mxm, 0.f);
    float vy = fmaxf(syy*rc - mym*mym, 0.f);
    float tv = vx + vy;
    geoO[((size_t)b*NN + px)*TK + k] = 1.0f / (1.0f + tv*100.0f);
  }
}

// ---------------- refine: K=8 softmax blend ----------------
extern "C" __global__ __launch_bounds__(256)
void k_refine(const float* __restrict__ tval, const float* __restrict__ tpos,
              const float* __restrict__ geo, const float* __restrict__ bexp,
              float* __restrict__ warpO, const float* __restrict__ gwp,
              const float* __restrict__ tpp){
  int id = blockIdx.x*256 + threadIdx.x;  // 0..8191
  float gw = fminf(fmaxf(gwp[0], 0.f), 2.f);
  float invt = 1.0f / tpp[0];
  size_t base = (size_t)id * TK;
  float c[8], px[8], py[8];
  float cm = -INFINITY;
  #pragma unroll
  for (int k = 0; k < 8; k++){
    c[k]  = tval[base + k] + gw * geo[base + k];
    px[k] = tpos[(base + k)*2 + 0]; py[k] = tpos[(base + k)*2 + 1];
    cm = fmaxf(cm, c[k]);
  }
  float Ws = 0.f, rx = 0.f, ry = 0.f;
  #pragma unroll
  for (int k = 0; k < 8; k++){
    float w = expf((c[k] - cm)*invt);
    Ws += w; rx = fmaf(w, px[k], rx); ry = fmaf(w, py[k], ry);
  }
  rx /= Ws; ry /= Ws;
  float bxv = bexp[id*2 + 0], byv = bexp[id*2 + 1];
  warpO[id*2 + 0] = bxv + (rx - bxv);
  warpO[id*2 + 1] = byv + (ry - byv);
}

extern "C" void kernel_launch(void* const* d_in, const int* in_sizes, int n_in,
                              void* d_out, int out_size, void* d_ws, size_t ws_size,
                              hipStream_t stream){
  (void)in_sizes; (void)n_in; (void)out_size; (void)ws_size;
  const float* fA   = (const float*)d_in[0];
  const float* fB   = (const float*)d_in[1];
  const float* posA = (const float*)d_in[2];
  const float* posB = (const float*)d_in[3];
  const float* dsp  = (const float*)d_in[4];
  const float* gwp  = (const float*)d_in[5];
  const float* tpp  = (const float*)d_in[6];

  float* out   = (float*)d_out;
  float* warpO = out;                                   // [2,4096,2]
  float* entO  = out + (size_t)BB*NN*2;                 // [2,4096]
  float* sim   = out + (size_t)BB*NN*2 + (size_t)BB*NN; // [2,4096,4096]
  float* geoO  = sim + (size_t)BB*NN*NN;                // [2,4096,8]

  float* u    = (float*)d_ws;                 // BB*USTR
  float* v    = u + BB*USTR;                  // BB*USTR
  float* pmax = v + BB*USTR;                  // BB*16*NN
  float* psum = pmax + BB*16*NN;              // BB*16*NN
  float* tval = psum + BB*16*NN;              // BB*NN*TK
  int*   tidx = (int*)(tval + BB*NN*TK);      // BB*NN*TK
  float* tpos = (float*)(tidx + BB*NN*TK);    // BB*NN*TK*2
  float* bexp = tpos + (size_t)BB*NN*TK*2;    // BB*NN*2
  float* nA   = bexp + BB*NN*2;               // BB*NN*CC
  float* nB   = nA + (size_t)BB*NN*CC;        // BB*NN*CC

  hipMemsetAsync(u, 0, sizeof(float)*(size_t)BB*USTR*2, stream);  // zero u,v

  k_norm<<<dim3(4096), dim3(256), 0, stream>>>(fA, fB, nA, nB);
  k_gemm<<<dim3(NN/128, NN/128, BB), dim3(256), 0, stream>>>(nA, nB, sim);

  for (int it = 0; it < 5; ++it){
    k_u <<<dim3(NN+1, BB), dim3(256), 0, stream>>>(sim, v, u, dsp, tpp);
    k_vA<<<dim3(16, 16, BB), dim3(256), 0, stream>>>(sim, u, pmax, psum, tpp);
    k_vB<<<dim3(17, 1, BB), dim3(256), 0, stream>>>(pmax, psum, u, v, dsp);
  }

  k_final<<<dim3(NN, BB), dim3(256), 0, stream>>>(sim, u, v, posB, entO,
                                                  tval, tidx, tpos, bexp, tpp);
  k_geo<<<dim3(TK, BB), dim3(1024), 0, stream>>>(posA, tpos, geoO);
  k_refine<<<dim3((BB*NN)/256), dim3(256), 0, stream>>>(tval, tpos, geoO, bexp,
                                                        warpO, gwp, tpp);
}

// Round 3
// 572.380 us; speedup vs baseline: 1.8154x; 1.8154x over previous
//
#include <hip/hip_runtime.h>
#include <math.h>

#define BB 2
#define NN 4096
#define CC 128
#define TK 8
#define USTR 4104

// f64-accurate constants, rounded by compiler to f32 (matches jnp.full(...f32))
#define NORM_C  (-9.010913347279288f)   // -log(8192)
#define DUST_C  (-0.6931471805599453f)  // log(4096) - log(8192)

__device__ __forceinline__ float block_sum4(float s, int t, float* sb){
  #pragma unroll
  for (int off = 32; off > 0; off >>= 1) s += __shfl_xor(s, off);
  if ((t & 63) == 0) sb[t >> 6] = s;
  __syncthreads();
  return sb[0] + sb[1] + sb[2] + sb[3];
}

// ---------------- normalize: both feats, one wave per row ----------------
extern "C" __global__ __launch_bounds__(256)
void k_norm(const float* __restrict__ fA, const float* __restrict__ fB,
            float* __restrict__ nA, float* __restrict__ nB){
  int gw   = (blockIdx.x * 256 + threadIdx.x) >> 6;   // global wave id
  int lane = threadIdx.x & 63;
  const float* src; float* dst;
  if (gw < BB*NN){ src = fA + (size_t)gw*CC; dst = nA + (size_t)gw*CC; }
  else { int r = gw - BB*NN; src = fB + (size_t)r*CC; dst = nB + (size_t)r*CC; }
  float2 x = ((const float2*)src)[lane];
  float ss = x.x*x.x + x.y*x.y;
  #pragma unroll
  for (int off = 32; off > 0; off >>= 1) ss += __shfl_xor(ss, off);
  float inv = 1.0f / fmaxf(sqrtf(ss), 1e-12f);
  ((float2*)dst)[lane] = make_float2(x.x*inv, x.y*inv);
}

// ---------------- f32 GEMM: sim = nA @ nB^T, 128x128 tile, 8x8 microtile ----------------
extern "C" __global__ __launch_bounds__(256)
void k_gemm(const float* __restrict__ nA, const float* __restrict__ nB, float* __restrict__ sim){
  __shared__ float sA[32][132];
  __shared__ float sB[32][132];
  const int t  = threadIdx.x;
  const int b  = blockIdx.z;
  const int m0 = blockIdx.y << 7, n0 = blockIdx.x << 7;
  const float* Ab = nA + ((size_t)b*NN + m0)*CC;
  const float* Bb = nB + ((size_t)b*NN + n0)*CC;
  const int tx = t & 15, ty = t >> 4;
  float acc[8][8];
  #pragma unroll
  for (int i = 0; i < 8; i++)
    #pragma unroll
    for (int j = 0; j < 8; j++) acc[i][j] = 0.f;

  #pragma unroll 1
  for (int kc = 0; kc < 4; kc++){
    if (kc) __syncthreads();
    #pragma unroll
    for (int i = 0; i < 4; i++){
      int fi = t + (i << 8);
      int r  = fi >> 3, c4 = fi & 7;
      float4 av = *(const float4*)(Ab + (size_t)r*CC + (kc<<5) + (c4<<2));
      float4 bv = *(const float4*)(Bb + (size_t)r*CC + (kc<<5) + (c4<<2));
      int kk = c4 << 2;
      sA[kk+0][r]=av.x; sA[kk+1][r]=av.y; sA[kk+2][r]=av.z; sA[kk+3][r]=av.w;
      sB[kk+0][r]=bv.x; sB[kk+1][r]=bv.y; sB[kk+2][r]=bv.z; sB[kk+3][r]=bv.w;
    }
    __syncthreads();
    #pragma unroll 4
    for (int k = 0; k < 32; k++){
      float4 a0 = *(const float4*)&sA[k][ty<<2];
      float4 a1 = *(const float4*)&sA[k][64 + (ty<<2)];
      float4 b0 = *(const float4*)&sB[k][tx<<2];
      float4 b1 = *(const float4*)&sB[k][64 + (tx<<2)];
      float av[8] = {a0.x,a0.y,a0.z,a0.w,a1.x,a1.y,a1.z,a1.w};
      float bw[8] = {b0.x,b0.y,b0.z,b0.w,b1.x,b1.y,b1.z,b1.w};
      #pragma unroll
      for (int i = 0; i < 8; i++)
        #pragma unroll
        for (int j = 0; j < 8; j++)
          acc[i][j] = fmaf(av[i], bw[j], acc[i][j]);
    }
  }
  float* Cb = sim + ((size_t)b*NN + m0)*NN + n0;
  #pragma unroll
  for (int i = 0; i < 8; i++){
    int mr = (i < 4) ? ((ty<<2) + i) : (64 + (ty<<2) + (i-4));
    float* cp = Cb + (size_t)mr*NN;
    *(float4*)(cp + (tx<<2))      = make_float4(acc[i][0],acc[i][1],acc[i][2],acc[i][3]);
    *(float4*)(cp + 64 + (tx<<2)) = make_float4(acc[i][4],acc[i][5],acc[i][6],acc[i][7]);
  }
}

// ---------------- Sinkhorn u-update: block per row, max-free exp-sum ----------------
extern "C" __global__ __launch_bounds__(256)
void k_u(const float* __restrict__ sim, const float* __restrict__ v, float* __restrict__ u,
         const float* __restrict__ dsp, const float* __restrict__ tpp){
  int row = blockIdx.x, b = blockIdx.y, t = threadIdx.x;
  float invt = 1.0f / tpp[0], ds = dsp[0];
  const float4* vb4 = (const float4*)(v + b*USTR);
  float s0 = 0.f, s1 = 0.f, s2 = 0.f, s3 = 0.f;
  if (row < NN){
    const float4* sr4 = (const float4*)(sim + ((size_t)b*NN + row)*NN);
    #pragma unroll
    for (int i = 0; i < 4; i++){
      int q = t + (i<<8);
      float4 sv = sr4[q]; float4 vv = vb4[q];
      s0 += __expf(fmaf(sv.x, invt, vv.x));
      s1 += __expf(fmaf(sv.y, invt, vv.y));
      s2 += __expf(fmaf(sv.z, invt, vv.z));
      s3 += __expf(fmaf(sv.w, invt, vv.w));
    }
  } else {
    #pragma unroll
    for (int i = 0; i < 4; i++){
      int q = t + (i<<8);
      float4 vv = vb4[q];
      s0 += __expf(ds + vv.x);
      s1 += __expf(ds + vv.y);
      s2 += __expf(ds + vv.z);
      s3 += __expf(ds + vv.w);
    }
  }
  float s = (s0 + s1) + (s2 + s3);
  if (t == 0) s += __expf((row < NN ? ds : 0.0f) + v[b*USTR + NN]);
  __shared__ float sb[4];
  float S = block_sum4(s, t, sb);
  if (t == 0) u[b*USTR + row] = (row < NN ? NORM_C : DUST_C) - __logf(S);
}

// ---------------- Sinkhorn v-update stage A: 64-row chunks, 4 cols/thread ----------------
extern "C" __global__ __launch_bounds__(256)
void k_vA(const float* __restrict__ sim, const float* __restrict__ u,
          float* __restrict__ psum, const float* __restrict__ tpp){
  int t = threadIdx.x;
  int c4 = blockIdx.x*256 + t;           // float4 column index 0..1023
  int chunk = blockIdx.y, b = blockIdx.z;
  float invt = 1.0f / tpp[0];
  __shared__ float su[64];
  if (t < 64) su[t] = u[b*USTR + (chunk<<6) + t];
  __syncthreads();
  const float4* sp = (const float4*)(sim + ((size_t)b*NN + (chunk<<6))*NN) + c4;
  float ax = 0.f, ay = 0.f, az = 0.f, aw = 0.f;
  #pragma unroll 8
  for (int r = 0; r < 64; r++){
    float4 sv = sp[(size_t)r*(NN/4)];
    float uu = su[r];
    ax += __expf(fmaf(sv.x, invt, uu));
    ay += __expf(fmaf(sv.y, invt, uu));
    az += __expf(fmaf(sv.z, invt, uu));
    aw += __expf(fmaf(sv.w, invt, uu));
  }
  ((float4*)(psum + ((size_t)(b*64 + chunk))*NN))[c4] = make_float4(ax, ay, az, aw);
}

// ---------------- Sinkhorn v-update stage B: merge 64 chunks + dustbin ----------------
extern "C" __global__ __launch_bounds__(256)
void k_vB(const float* __restrict__ psum, const float* __restrict__ u,
          float* __restrict__ v, const float* __restrict__ dsp){
  int t = threadIdx.x, b = blockIdx.z;
  float ds = dsp[0];
  if (blockIdx.x < 16){
    int n = blockIdx.x*256 + t;
    float s = 0.f;
    #pragma unroll 16
    for (int c = 0; c < 64; c++) s += psum[((size_t)(b*64 + c))*NN + n];
    s += __expf(ds + u[b*USTR + NN]);
    v[b*USTR + n] = NORM_C - __logf(s);
  } else {
    float s0 = 0.f;
    #pragma unroll
    for (int i = 0; i < 16; i++){ int m = t + (i<<8); s0 += __expf(ds + u[b*USTR + m]); }
    if (t == 0) s0 += __expf(u[b*USTR + NN]);
    __shared__ float sb[4];
    float S = block_sum4(s0, t, sb);
    if (t == 0) v[b*USTR + NN] = DUST_C - __logf(S);
  }
}

// ---------------- final fused row pass: probs, entropy, base_expected, top-8 ----------------
extern "C" __global__ __launch_bounds__(256)
void k_final(const float* __restrict__ sim, const float* __restrict__ u, const float* __restrict__ v,
             const float* __restrict__ posB, float* __restrict__ entO,
             float* __restrict__ tval, int* __restrict__ tidx, float* __restrict__ tpos,
             float* __restrict__ bexp, const float* __restrict__ tpp){
  int m = blockIdx.x, b = blockIdx.y, t = threadIdx.x;
  float invt = 1.0f / tpp[0];
  const float4* sr4 = (const float4*)(sim + ((size_t)b*NN + m)*NN);
  const float4* vb4 = (const float4*)(v + b*USTR);
  float um = u[b*USTR + m];
  float p[16];
  float s_loc = 0.f;
  #pragma unroll
  for (int i = 0; i < 4; i++){
    int q = t + (i<<8);
    float4 sv = sr4[q]; float4 vv = vb4[q];
    p[4*i+0] = __expf(fmaf(sv.x, invt, um + vv.x));
    p[4*i+1] = __expf(fmaf(sv.y, invt, um + vv.y));
    p[4*i+2] = __expf(fmaf(sv.z, invt, um + vv.z));
    p[4*i+3] = __expf(fmaf(sv.w, invt, um + vv.w));
    s_loc += (p[4*i+0] + p[4*i+1]) + (p[4*i+2] + p[4*i+3]);
  }
  __shared__ float rs[4];
  float Sp = block_sum4(s_loc, t, rs) + 1e-8f;

  const float4* pb4 = (const float4*)(posB + (size_t)b*NN*2);
  float e = 0.f, bx = 0.f, by = 0.f;
  #pragma unroll
  for (int i = 0; i < 4; i++){
    int q = t + (i<<8);
    float4 q01 = pb4[2*q];      // x0,y0,x1,y1
    float4 q23 = pb4[2*q + 1];  // x2,y2,x3,y3
    float pd0 = p[4*i+0] / Sp, pd1 = p[4*i+1] / Sp;
    float pd2 = p[4*i+2] / Sp, pd3 = p[4*i+3] / Sp;
    e -= pd0 * __logf(pd0 + 1e-8f) + pd1 * __logf(pd1 + 1e-8f)
       + pd2 * __logf(pd2 + 1e-8f) + pd3 * __logf(pd3 + 1e-8f);
    bx = fmaf(pd0, q01.x, bx); by = fmaf(pd0, q01.y, by);
    bx = fmaf(pd1, q01.z, bx); by = fmaf(pd1, q01.w, by);
    bx = fmaf(pd2, q23.x, bx); by = fmaf(pd2, q23.y, by);
    bx = fmaf(pd3, q23.z, bx); by = fmaf(pd3, q23.w, by);
  }
  #pragma unroll
  for (int off = 32; off > 0; off >>= 1){
    e  += __shfl_xor(e, off);
    bx += __shfl_xor(bx, off);
    by += __shfl_xor(by, off);
  }
  __shared__ float re[4], rbx[4], rby[4];
  if ((t & 63) == 0){ re[t>>6] = e; rbx[t>>6] = bx; rby[t>>6] = by; }
  __syncthreads();
  if (t == 0){
    entO[(size_t)b*NN + m] = re[0]+re[1]+re[2]+re[3];
    bexp[((size_t)b*NN + m)*2 + 0] = rbx[0]+rbx[1]+rbx[2]+rbx[3];
    bexp[((size_t)b*NN + m)*2 + 1] = rby[0]+rby[1]+rby[2]+rby[3];
  }

  // top-8 (jax tie-break: lower index wins). col of p[j]: n = (t + (j>>2)*256)*4 + (j&3)
  __shared__ float wv[4]; __shared__ int wi[4];
  size_t obase = ((size_t)b*NN + m)*TK;
  for (int r = 0; r < TK; r++){
    float bv = -INFINITY; int bi = 0x7fffffff;
    #pragma unroll
    for (int j = 0; j < 16; j++){
      int n = ((t + ((j>>2)<<8)) << 2) + (j & 3);
      if (p[j] > bv){ bv = p[j]; bi = n; }
    }
    #pragma unroll
    for (int off = 32; off > 0; off >>= 1){
      float ov = __shfl_xor(bv, off); int oi = __shfl_xor(bi, off);
      if (ov > bv || (ov == bv && oi < bi)){ bv = ov; bi = oi; }
    }
    if ((t & 63) == 0){ wv[t>>6] = bv; wi[t>>6] = bi; }
    __syncthreads();
    float Wv = wv[0]; int Wi = wi[0];
    #pragma unroll
    for (int i = 1; i < 4; i++){ if (wv[i] > Wv || (wv[i] == Wv && wi[i] < Wi)){ Wv = wv[i]; Wi = wi[i]; } }
    if (t == ((Wi >> 2) & 255)){
      int sl = ((Wi >> 10) << 2) | (Wi & 3);
      #pragma unroll
      for (int j = 0; j < 16; j++) if (j == sl) p[j] = -INFINITY;  // static idx only
    }
    if (t == 0){
      tval[obase + r] = Wv; tidx[obase + r] = Wi;
      tpos[(obase + r)*2 + 0] = posB[((size_t)b*NN + Wi)*2 + 0];
      tpos[(obase + r)*2 + 1] = posB[((size_t)b*NN + Wi)*2 + 1];
    }
    __syncthreads();
  }
}

// ---------------- geometric scores: per (b,k) 64x64 disp image, 7x7 box stats ----------------
extern "C" __global__ __launch_bounds__(1024)
void k_geo(const float* __restrict__ posA, const float* __restrict__ tpos,
           float* __restrict__ geoO){
  int k = blockIdx.x, b = blockIdx.y, t = threadIdx.x;
  __shared__ float dx[4096], dy[4096];
  #pragma unroll
  for (int i = 0; i < 4; i++){
    int px = t + (i<<10);
    float2 c = *(const float2*)(tpos + (((size_t)b*NN + px)*TK + k)*2);
    float2 s = *(const float2*)(posA + ((size_t)b*NN + px)*2);
    dx[px] = c.x - s.x; dy[px] = c.y - s.y;
  }
  __syncthreads();
  #pragma unroll
  for (int i = 0; i < 4; i++){
    int px = t + (i<<10);
    int h = px >> 6, w = px & 63;
    int h0 = max(h-3, 0), h1 = min(h+3, 63);
    int w0 = max(w-3, 0), w1 = min(w+3, 63);
    float sx = 0.f, sxx = 0.f, sy = 0.f, syy = 0.f;
    for (int hh = h0; hh <= h1; hh++){
      int ro = hh << 6;
      for (int ww = w0; ww <= w1; ww++){
        float a = dx[ro + ww]; sx += a; sxx = fmaf(a, a, sxx);
        float c2 = dy[ro + ww]; sy += c2; syy = fmaf(c2, c2, syy);
      }
    }
    float rc = 1.0f / (float)((h1-h0+1)*(w1-w0+1));
    float mxm = sx*rc, mym = sy*rc;
    float vx = fmaxf(sxx*rc - mxm*mxm, 0.f);
    float vy = fmaxf(syy*rc - mym*mym, 0.f);
    float tv = vx + vy;
    geoO[((size_t)b*NN + px)*TK + k] = 1.0f / (1.0f + tv*100.0f);
  }
}

// ---------------- refine: K=8 softmax blend ----------------
extern "C" __global__ __launch_bounds__(256)
void k_refine(const float* __restrict__ tval, const float* __restrict__ tpos,
              const float* __restrict__ geo, const float* __restrict__ bexp,
              float* __restrict__ warpO, const float* __restrict__ gwp,
              const float* __restrict__ tpp){
  int id = blockIdx.x*256 + threadIdx.x;
  float gw = fminf(fmaxf(gwp[0], 0.f), 2.f);
  float invt = 1.0f / tpp[0];
  size_t base = (size_t)id * TK;
  float c[8], px[8], py[8];
  float cm = -INFINITY;
  #pragma unroll
  for (int k = 0; k < 8; k++){
    c[k]  = tval[base + k] + gw * geo[base + k];
    px[k] = tpos[(base + k)*2 + 0]; py[k] = tpos[(base + k)*2 + 1];
    cm = fmaxf(cm, c[k]);
  }
  float Ws = 0.f, rx = 0.f, ry = 0.f;
  #pragma unroll
  for (int k = 0; k < 8; k++){
    float w = expf((c[k] - cm)*invt);
    Ws += w; rx = fmaf(w, px[k], rx); ry = fmaf(w, py[k], ry);
  }
  rx /= Ws; ry /= Ws;
  float bxv = bexp[id*2 + 0], byv = bexp[id*2 + 1];
  warpO[id*2 + 0] = bxv + (rx - bxv);
  warpO[id*2 + 1] = byv + (ry - byv);
}

extern "C" void kernel_launch(void* const* d_in, const int* in_sizes, int n_in,
                              void* d_out, int out_size, void* d_ws, size_t ws_size,
                              hipStream_t stream){
  (void)in_sizes; (void)n_in; (void)out_size; (void)ws_size;
  const float* fA   = (const float*)d_in[0];
  const float* fB   = (const float*)d_in[1];
  const float* posA = (const float*)d_in[2];
  const float* posB = (const float*)d_in[3];
  const float* dsp  = (const float*)d_in[4];
  const float* gwp  = (const float*)d_in[5];
  const float* tpp  = (const float*)d_in[6];

  float* out   = (float*)d_out;
  float* warpO = out;                                   // [2,4096,2]
  float* entO  = out + (size_t)BB*NN*2;                 // [2,4096]
  float* sim   = out + (size_t)BB*NN*2 + (size_t)BB*NN; // [2,4096,4096]
  float* geoO  = sim + (size_t)BB*NN*NN;                // [2,4096,8]

  float* u    = (float*)d_ws;                 // BB*USTR
  float* v    = u + BB*USTR;                  // BB*USTR
  float* psum = v + BB*USTR;                  // BB*64*NN
  float* tval = psum + (size_t)BB*64*NN;      // BB*NN*TK
  int*   tidx = (int*)(tval + BB*NN*TK);      // BB*NN*TK
  float* tpos = (float*)(tidx + BB*NN*TK);    // BB*NN*TK*2
  float* bexp = tpos + (size_t)BB*NN*TK*2;    // BB*NN*2
  float* nA   = bexp + BB*NN*2;               // BB*NN*CC
  float* nB   = nA + (size_t)BB*NN*CC;        // BB*NN*CC

  hipMemsetAsync(u, 0, sizeof(float)*(size_t)BB*USTR*2, stream);  // zero u,v

  k_norm<<<dim3(4096), dim3(256), 0, stream>>>(fA, fB, nA, nB);
  k_gemm<<<dim3(NN/128, NN/128, BB), dim3(256), 0, stream>>>(nA, nB, sim);

  for (int it = 0; it < 5; ++it){
    k_u <<<dim3(NN+1, BB), dim3(256), 0, stream>>>(sim, v, u, dsp, tpp);
    k_vA<<<dim3(4, 64, BB), dim3(256), 0, stream>>>(sim, u, psum, tpp);
    k_vB<<<dim3(17, 1, BB), dim3(256), 0, stream>>>(psum, u, v, dsp);
  }

  k_final<<<dim3(NN, BB), dim3(256), 0, stream>>>(sim, u, v, posB, entO,
                                                  tval, tidx, tpos, bexp, tpp);
  k_geo<<<dim3(TK, BB), dim3(1024), 0, stream>>>(posA, tpos, geoO);
  k_refine<<<dim3((BB*NN)/256), dim3(256), 0, stream>>>(tval, tpos, geoO, bexp,
                                                        warpO, gwp, tpp);
}